// Round 5
// baseline (3043.572 us; speedup 1.0000x reference)
//
#include <hip/hip_runtime.h>

typedef _Float16 half_t;
typedef half_t half8 __attribute__((ext_vector_type(8)));
typedef half_t half4 __attribute__((ext_vector_type(4)));
typedef float  floatx4 __attribute__((ext_vector_type(4)));

#define NB 2048
#define NT 20
#define CD 512
#define HD 1024
#define VD 2048
#define QD 1024
#define NBHD ((size_t)NB * HD)
#define MALL (NB * NT)          // 40960 rows for batched GEMMs

// LDS row stride 72 halves (144 B): fragment reads land on bank-quads 4r%32
// -> 2-way aliasing only (free, m136).
#define LDST 72

__device__ __forceinline__ float sigmoidf_(float x) {
    return 1.0f / (1.0f + __expf(-x));
}
__device__ __forceinline__ float tanhf_(float x) {
    return 1.0f - 2.0f / (1.0f + __expf(2.0f * x));
}
__device__ __forceinline__ float lrelu_(float x) {
    return x > 0.0f ? x : 0.01f * x;
}

// ---- 128x64-tile GEMM core, BK=64, 256 threads = 4 waves (2x2) ----
// Per wave: 64m x 32n output = 4x2 fragments of 16x16x32 -> 12 ds_read_b128
// per 16 MFMA (~0.75 KB LDS/MFMA). R4's 32-row/NG=3 shape needed ~1.8 KB
// LDS/MFMA and was LDS-throughput-bound (~660 LDS cyc vs 58 MFMA cyc/iter).
// C[m0..+128, c0..+64] += A[M,K] @ W[N,K]^T. lds needs 192*LDST halves (27KB).
__device__ __forceinline__ void gemm_core(
    const half_t* __restrict__ A, const half_t* __restrict__ W,
    int K, int m0, int c0, half_t* lds, floatx4 (*acc)[2])
{
    const int tid  = threadIdx.x;
    const int lane = tid & 63;
    const int wid  = tid >> 6;
    const int wr   = (wid >> 1) * 64;
    const int wc   = (wid & 1) * 32;
    const int frow = lane & 15;
    const int fk   = (lane >> 4) * 8;
    half_t* ldsB = lds + 128 * LDST;

    for (int k0 = 0; k0 < K; k0 += 64) {
        __syncthreads();
#pragma unroll
        for (int i = 0; i < 4; ++i) {           // A tile: 128 rows x 64 k
            const int idx = tid + i * 256;      // 0..1023
            const int r = idx >> 3, ch = (idx & 7) * 8;
            *(uint4*)(lds + r * LDST + ch) =
                *(const uint4*)(A + (size_t)(m0 + r) * K + k0 + ch);
        }
#pragma unroll
        for (int i = 0; i < 2; ++i) {           // W tile: 64 rows x 64 k
            const int idx = tid + i * 256;      // 0..511
            const int r = idx >> 3, ch = (idx & 7) * 8;
            *(uint4*)(ldsB + r * LDST + ch) =
                *(const uint4*)(W + (size_t)(c0 + r) * K + k0 + ch);
        }
        __syncthreads();
#pragma unroll
        for (int kk = 0; kk < 2; ++kk) {
            half8 bf[2];
#pragma unroll
            for (int in = 0; in < 2; ++in)
                bf[in] = *(const half8*)(ldsB + (wc + in * 16 + frow) * LDST + kk * 32 + fk);
#pragma unroll
            for (int im = 0; im < 4; ++im) {
                half8 af = *(const half8*)(lds + (wr + im * 16 + frow) * LDST + kk * 32 + fk);
#pragma unroll
                for (int in = 0; in < 2; ++in)
                    acc[im][in] = __builtin_amdgcn_mfma_f32_16x16x32_f16(
                        af, bf[in], acc[im][in], 0, 0, 0);
            }
        }
    }
}

__device__ __forceinline__ void zero8(floatx4 (*acc)[2]) {
#pragma unroll
    for (int im = 0; im < 4; ++im)
#pragma unroll
        for (int in = 0; in < 2; ++in)
            acc[im][in] = (floatx4){0.f, 0.f, 0.f, 0.f};
}

// fp32 -> fp16, 4 elems/thread
__global__ void cvt_kernel(const float* __restrict__ src, half_t* __restrict__ dst, int n) {
    int i = (blockIdx.x * 256 + threadIdx.x) * 4;
    if (i < n) {
        float4 f = *(const float4*)(src + i);
        half4 h = {(half_t)f.x, (half_t)f.y, (half_t)f.z, (half_t)f.w};
        *(half4*)(dst + i) = h;
    }
}

// pack w2cat[c][0:512]=wih2[c][:], w2cat[c][512:1536]=whh2[c][:] (fp32->fp16)
__global__ void pack_w2_kernel(const float* __restrict__ w_ih2,
                               const float* __restrict__ w_hh2,
                               half_t* __restrict__ w2cat) {
    int i = blockIdx.x * 256 + threadIdx.x;       // 0 .. 3072*1536/4-1
    int c = i / 384, kq = (i % 384) * 4;
    float4 f = (kq < CD) ? *(const float4*)(w_ih2 + (size_t)c * CD + kq)
                         : *(const float4*)(w_hh2 + (size_t)c * HD + (kq - CD));
    half4 h = {(half_t)f.x, (half_t)f.y, (half_t)f.z, (half_t)f.w};
    *(half4*)(w2cat + (size_t)c * (CD + HD) + kq) = h;
}

// fvq = leaky(v@Wv^T) + leaky(q@Wq^T), fp32 [NB,CD]
__global__ __launch_bounds__(256) void fvq_kernel(
    const half_t* __restrict__ v_h, const half_t* __restrict__ wv_h,
    const half_t* __restrict__ q_h, const half_t* __restrict__ wq_h,
    float* __restrict__ fvq)
{
    __shared__ half_t lds[192 * LDST];
    floatx4 a1[4][2], a2[4][2];
    zero8(a1); zero8(a2);
    const int m0 = blockIdx.y * 128, c0 = blockIdx.x * 64;
    gemm_core(v_h, wv_h, VD, m0, c0, lds, a1);
    gemm_core(q_h, wq_h, QD, m0, c0, lds, a2);
    const int lane = threadIdx.x & 63, wid = threadIdx.x >> 6;
    const int wr = (wid >> 1) * 64, wc = (wid & 1) * 32;
#pragma unroll
    for (int im = 0; im < 4; ++im)
#pragma unroll
    for (int in = 0; in < 2; ++in) {
        const int mb = m0 + wr + im * 16 + (lane >> 4) * 4;
        const int c  = c0 + wc + in * 16 + (lane & 15);
#pragma unroll
        for (int j = 0; j < 4; ++j)
            fvq[(size_t)(mb + j) * CD + c] = lrelu_(a1[im][in][j]) + lrelu_(a2[im][in][j]);
    }
}

// gi1_all = caption @ wih1^T over all (m,t) rows: [MALL][3CD] fp16 (no bias)
__global__ __launch_bounds__(256) void gi1_gemm_kernel(
    const half_t* __restrict__ cap_h, const half_t* __restrict__ wih1,
    half_t* __restrict__ gi1_all)
{
    __shared__ half_t lds[192 * LDST];
    floatx4 acc[4][2];
    zero8(acc);
    const int m0 = blockIdx.y * 128, c0 = blockIdx.x * 64;
    gemm_core(cap_h, wih1, CD, m0, c0, lds, acc);
    const int lane = threadIdx.x & 63, wid = threadIdx.x >> 6;
    const int wr = (wid >> 1) * 64, wc = (wid & 1) * 32;
#pragma unroll
    for (int im = 0; im < 4; ++im)
#pragma unroll
    for (int in = 0; in < 2; ++in) {
        const int mb = m0 + wr + im * 16 + (lane >> 4) * 4;
        const int c  = c0 + wc + in * 16 + (lane & 15);
#pragma unroll
        for (int j = 0; j < 4; ++j)
            gi1_all[(size_t)(mb + j) * (3 * CD) + c] = (half_t)acc[im][in][j];
    }
}

// gates1 = h1 @ whh1^T  [NB][3CD] fp16 (no bias)
__global__ __launch_bounds__(256) void gates1_gemm_kernel(
    const half_t* __restrict__ h1, const half_t* __restrict__ whh1,
    half_t* __restrict__ gates1)
{
    __shared__ half_t lds[192 * LDST];
    floatx4 acc[4][2];
    zero8(acc);
    const int m0 = blockIdx.y * 128, c0 = blockIdx.x * 64;
    gemm_core(h1, whh1, CD, m0, c0, lds, acc);
    const int lane = threadIdx.x & 63, wid = threadIdx.x >> 6;
    const int wr = (wid >> 1) * 64, wc = (wid & 1) * 32;
#pragma unroll
    for (int im = 0; im < 4; ++im)
#pragma unroll
    for (int in = 0; in < 2; ++in) {
        const int mb = m0 + wr + im * 16 + (lane >> 4) * 4;
        const int c  = c0 + wc + in * 16 + (lane & 15);
#pragma unroll
        for (int j = 0; j < 4; ++j)
            gates1[(size_t)(mb + j) * (3 * CD) + c] = (half_t)acc[im][in][j];
    }
}

// gates2 = [att|h2] @ [wih2|whh2]^T  (K = 1536)  [NB][3HD] fp16
__global__ __launch_bounds__(256) void gates2_gemm_kernel(
    const half_t* __restrict__ atth2, const half_t* __restrict__ w2cat,
    half_t* __restrict__ gates2)
{
    __shared__ half_t lds[192 * LDST];
    floatx4 acc[4][2];
    zero8(acc);
    const int m0 = blockIdx.y * 128, c0 = blockIdx.x * 64;
    gemm_core(atth2, w2cat, CD + HD, m0, c0, lds, acc);
    const int lane = threadIdx.x & 63, wid = threadIdx.x >> 6;
    const int wr = (wid >> 1) * 64, wc = (wid & 1) * 32;
#pragma unroll
    for (int im = 0; im < 4; ++im)
#pragma unroll
    for (int in = 0; in < 2; ++in) {
        const int mb = m0 + wr + im * 16 + (lane >> 4) * 4;
        const int c  = c0 + wc + in * 16 + (lane & 15);
#pragma unroll
        for (int j = 0; j < 4; ++j)
            gates2[(size_t)(mb + j) * (3 * HD) + c] = (half_t)acc[im][in][j];
    }
}

// fc_out[t*NB+m][c] = (t<cap_len[m]) ? lrelu(h2[t+1] @ wfc^T) : 0   fp16
__global__ __launch_bounds__(256) void fc_gemm_kernel(
    const half_t* __restrict__ h2_rows,   // h2_all + NBHD: rows r = t*NB+m
    const half_t* __restrict__ wfc, const int* __restrict__ cap_len,
    half_t* __restrict__ fc_out)
{
    __shared__ half_t lds[192 * LDST];
    floatx4 acc[4][2];
    zero8(acc);
    const int m0 = blockIdx.y * 128, c0 = blockIdx.x * 64;
    gemm_core(h2_rows, wfc, HD, m0, c0, lds, acc);
    const int lane = threadIdx.x & 63, wid = threadIdx.x >> 6;
    const int wr = (wid >> 1) * 64, wc = (wid & 1) * 32;
#pragma unroll
    for (int im = 0; im < 4; ++im) {
        const int rb = m0 + wr + im * 16 + (lane >> 4) * 4;
#pragma unroll
        for (int j = 0; j < 4; ++j) {
            const int r = rb + j;
            const int t = r >> 11, m = r & (NB - 1);
            const bool act = t < cap_len[m];
#pragma unroll
            for (int in = 0; in < 2; ++in) {
                const int c = c0 + wc + in * 16 + (lane & 15);
                fc_out[(size_t)r * HD + c] = act ? (half_t)lrelu_(acc[im][in][j]) : (half_t)0.f;
            }
        }
    }
}

// out[m][c] = max_t fc_out[t][m][c]  (a zero slice always exists: cap_len<=19)
__global__ __launch_bounds__(256) void reduce_max_kernel(
    const half_t* __restrict__ fc_out, float* __restrict__ outmax)
{
    const size_t idx = ((size_t)blockIdx.x * 256 + threadIdx.x) * 8;
    float mx[8];
#pragma unroll
    for (int j = 0; j < 8; ++j) mx[j] = 0.f;
    for (int t = 0; t < NT; ++t) {
        half8 v = *(const half8*)(fc_out + (size_t)t * NBHD + idx);
#pragma unroll
        for (int j = 0; j < 8; ++j) mx[j] = fmaxf(mx[j], (float)v[j]);
    }
    float4 o0 = {mx[0], mx[1], mx[2], mx[3]}, o1 = {mx[4], mx[5], mx[6], mx[7]};
    *(float4*)(outmax + idx)     = o0;
    *(float4*)(outmax + idx + 4) = o1;
}

// GRU1 pointwise: h1' from gi1_all+gates1; att; alphas. 8 c's per thread.
__global__ __launch_bounds__(256) void gru1_kernel(
    const half_t* __restrict__ gates1, const half_t* __restrict__ gi1_all,
    const half_t* __restrict__ cap_h,
    const float* __restrict__ b_ih1, const float* __restrict__ b_hh1,
    const half_t* __restrict__ h1_src, half_t* __restrict__ h1_dst,
    const float* __restrict__ fvq, const int* __restrict__ cap_len,
    half_t* __restrict__ atth2, float* __restrict__ alphas, int t)
{
    const int i = blockIdx.x * 256 + threadIdx.x;   // 0..NB*CD/8-1
    const int m = i >> 6;
    const int c = (i & 63) << 3;
    const bool act = t < cap_len[m];
    const size_t g1 = (size_t)m * (3 * CD) + c;
    const size_t gi = ((size_t)m * NT + t) * (3 * CD) + c;
    half8 ghr = *(const half8*)(gates1 + g1);
    half8 ghz = *(const half8*)(gates1 + g1 + CD);
    half8 ghn = *(const half8*)(gates1 + g1 + 2 * CD);
    half8 gir = *(const half8*)(gi1_all + gi);
    half8 giz = *(const half8*)(gi1_all + gi + CD);
    half8 gin = *(const half8*)(gi1_all + gi + 2 * CD);
    half8 xv  = *(const half8*)(cap_h + ((size_t)m * NT + t) * CD + c);
    half8 ho  = *(const half8*)(h1_src + (size_t)m * CD + c);
    half8 hn, at;
    float al[8];
#pragma unroll
    for (int j = 0; j < 8; ++j) {
        const float r = sigmoidf_((float)gir[j] + b_ih1[c + j] + (float)ghr[j] + b_hh1[c + j]);
        const float z = sigmoidf_((float)giz[j] + b_ih1[CD + c + j] + (float)ghz[j] + b_hh1[CD + c + j]);
        const float n = tanhf_((float)gin[j] + b_ih1[2 * CD + c + j] +
                               r * ((float)ghn[j] + b_hh1[2 * CD + c + j]));
        const float h = act ? (1.f - z) * n + z * (float)ho[j] : (float)ho[j];
        const float a = sigmoidf_(h * fvq[(size_t)m * CD + c + j]) * (float)xv[j];
        hn[j] = (half_t)h; at[j] = (half_t)a;
        al[j] = act ? a : 0.f;
    }
    *(half8*)(h1_dst + (size_t)m * CD + c) = hn;
    *(half8*)(atth2 + (size_t)m * (CD + HD) + c) = at;
    float* ap = alphas + ((size_t)m * NT + t) * CD + c;
    *(float4*)ap       = (float4){al[0], al[1], al[2], al[3]};
    *(float4*)(ap + 4) = (float4){al[4], al[5], al[6], al[7]};
}

// GRU2 pointwise: h2' from gates2 (+biases); writes h2_all slice & atth2.
__global__ __launch_bounds__(256) void gru2_kernel(
    const half_t* __restrict__ gates2,
    const float* __restrict__ b_ih2, const float* __restrict__ b_hh2,
    const half_t* __restrict__ h2_src, half_t* __restrict__ h2_dst,
    const int* __restrict__ cap_len, half_t* __restrict__ atth2, int t)
{
    const int i = blockIdx.x * 256 + threadIdx.x;   // 0..NB*HD/8-1
    const int m = i >> 7;
    const int c = (i & 127) << 3;
    const bool act = t < cap_len[m];
    const size_t g2 = (size_t)m * (3 * HD) + c;
    half8 gr = *(const half8*)(gates2 + g2);
    half8 gz = *(const half8*)(gates2 + g2 + HD);
    half8 gn = *(const half8*)(gates2 + g2 + 2 * HD);
    half8 ho = *(const half8*)(h2_src + (size_t)m * HD + c);
    half8 hn;
#pragma unroll
    for (int j = 0; j < 8; ++j) {
        // gates2 already holds gi+gh (concatenated GEMM); add both biases
        const float r = sigmoidf_((float)gr[j] + b_ih2[c + j] + b_hh2[c + j]);
        const float z = sigmoidf_((float)gz[j] + b_ih2[HD + c + j] + b_hh2[HD + c + j]);
        // n-gate: tanh(gi_n + b_ih + r*(gh_n + b_hh)) — but gi_n and gh_n were
        // summed by the GEMM. Recover: we need r*(gh_n+b_hh) + gi_n + b_ih.
        // Trick not possible post-sum -> see gates2 layout note below.
        hn[j] = (half_t)0.f; (void)r; (void)z;
    }
    (void)hn; (void)act; (void)h2_dst; (void)atth2; (void)t; (void)cap_len; (void)gn; (void)ho;
}

extern "C" void kernel_launch(void* const* d_in, const int* in_sizes, int n_in,
                              void* d_out, int out_size, void* d_ws, size_t ws_size,
                              hipStream_t stream);

// ---------------------------------------------------------------------------
// NOTE: the n-gate needs r * (gh_n) separately from gi_n, so gi2 and gh2 must
// NOT be pre-summed. Fix: w2cat n-gate block keeps wih2_n and whh2_n SPLIT by
// producing 4 output groups: [r(sum) | z(sum) | n_i | n_h], i.e. N = 4*HD.
// Implemented below via w2cat layout [4HD][1536] where rows:
//   [0,HD):   wih2_r | whh2_r      (summed r-gate: A=[att|h2] covers both)
//   [HD,2HD): wih2_z | whh2_z
//   [2HD,3HD): wih2_n | 0          (gi_n: h2 part zeroed)
//   [3HD,4HD): 0      | whh2_n     (gh_n: att part zeroed)
// ---------------------------------------------------------------------------

__global__ void pack_w2v2_kernel(const float* __restrict__ w_ih2,
                                 const float* __restrict__ w_hh2,
                                 half_t* __restrict__ w2cat) {
    const int i = blockIdx.x * 256 + threadIdx.x;   // 0 .. 4*HD*1536/4 - 1
    const int row = i / 384, kq = (i % 384) * 4;    // row in [0,4HD), kq in [0,1536)
    const int gate = row >> 10;                     // 0=r,1=z,2=n_i,3=n_h
    const int c = row & (HD - 1);
    float4 f = {0.f, 0.f, 0.f, 0.f};
    if (gate < 2) {
        f = (kq < CD) ? *(const float4*)(w_ih2 + (size_t)(gate * HD + c) * CD + kq)
                      : *(const float4*)(w_hh2 + (size_t)(gate * HD + c) * HD + (kq - CD));
    } else if (gate == 2) {
        if (kq < CD) f = *(const float4*)(w_ih2 + (size_t)(2 * HD + c) * CD + kq);
    } else {
        if (kq >= CD) f = *(const float4*)(w_hh2 + (size_t)(2 * HD + c) * HD + (kq - CD));
    }
    half4 h = {(half_t)f.x, (half_t)f.y, (half_t)f.z, (half_t)f.w};
    *(half4*)(w2cat + (size_t)row * (CD + HD) + kq) = h;
}

// real GRU2 pointwise over gates2 [NB][4HD]
__global__ __launch_bounds__(256) void gru2v2_kernel(
    const half_t* __restrict__ gates2,
    const float* __restrict__ b_ih2, const float* __restrict__ b_hh2,
    const half_t* __restrict__ h2_src, half_t* __restrict__ h2_dst,
    const int* __restrict__ cap_len, half_t* __restrict__ atth2, int t)
{
    const int i = blockIdx.x * 256 + threadIdx.x;
    const int m = i >> 7;
    const int c = (i & 127) << 3;
    const bool act = t < cap_len[m];
    const size_t g2 = (size_t)m * (4 * HD) + c;
    half8 gr  = *(const half8*)(gates2 + g2);
    half8 gz  = *(const half8*)(gates2 + g2 + HD);
    half8 gni = *(const half8*)(gates2 + g2 + 2 * HD);
    half8 gnh = *(const half8*)(gates2 + g2 + 3 * HD);
    half8 ho  = *(const half8*)(h2_src + (size_t)m * HD + c);
    half8 hn;
#pragma unroll
    for (int j = 0; j < 8; ++j) {
        const float r = sigmoidf_((float)gr[j] + b_ih2[c + j] + b_hh2[c + j]);
        const float z = sigmoidf_((float)gz[j] + b_ih2[HD + c + j] + b_hh2[HD + c + j]);
        const float n = tanhf_((float)gni[j] + b_ih2[2 * HD + c + j] +
                               r * ((float)gnh[j] + b_hh2[2 * HD + c + j]));
        hn[j] = (half_t)(act ? (1.f - z) * n + z * (float)ho[j] : (float)ho[j]);
    }
    *(half8*)(h2_dst + (size_t)m * HD + c) = hn;
    *(half8*)(atth2 + (size_t)m * (CD + HD) + CD + c) = hn;
}

// gates2 GEMM v2: N = 4*HD
__global__ __launch_bounds__(256) void gates2v2_gemm_kernel(
    const half_t* __restrict__ atth2, const half_t* __restrict__ w2cat,
    half_t* __restrict__ gates2)
{
    __shared__ half_t lds[192 * LDST];
    floatx4 acc[4][2];
    zero8(acc);
    const int m0 = blockIdx.y * 128, c0 = blockIdx.x * 64;
    gemm_core(atth2, w2cat, CD + HD, m0, c0, lds, acc);
    const int lane = threadIdx.x & 63, wid = threadIdx.x >> 6;
    const int wr = (wid >> 1) * 64, wc = (wid & 1) * 32;
#pragma unroll
    for (int im = 0; im < 4; ++im)
#pragma unroll
    for (int in = 0; in < 2; ++in) {
        const int mb = m0 + wr + im * 16 + (lane >> 4) * 4;
        const int c  = c0 + wc + in * 16 + (lane & 15);
#pragma unroll
        for (int j = 0; j < 4; ++j)
            gates2[(size_t)(mb + j) * (4 * HD) + c] = (half_t)acc[im][in][j];
    }
}

extern "C" void kernel_launch(void* const* d_in, const int* in_sizes, int n_in,
                              void* d_out, int out_size, void* d_ws, size_t ws_size,
                              hipStream_t stream)
{
    (void)in_sizes; (void)n_in; (void)out_size; (void)ws_size;
    const float* v     = (const float*)d_in[0];
    const float* q     = (const float*)d_in[1];
    const float* cap   = (const float*)d_in[2];
    const int*   cap_len = (const int*)d_in[3];
    const float* w_ih1 = (const float*)d_in[4];
    const float* w_hh1 = (const float*)d_in[5];
    const float* b_ih1 = (const float*)d_in[6];
    const float* b_hh1 = (const float*)d_in[7];
    const float* w_ih2 = (const float*)d_in[8];
    const float* w_hh2 = (const float*)d_in[9];
    const float* b_ih2 = (const float*)d_in[10];
    const float* b_hh2 = (const float*)d_in[11];
    const float* Wv    = (const float*)d_in[12];
    const float* Wq    = (const float*)d_in[13];
    const float* Wfc   = (const float*)d_in[14];

    float* out_max = (float*)d_out;            // [NB, HD]
    float* alphas  = (float*)d_out + NBHD;     // [NB, NT, CD]

    half_t* p = (half_t*)d_ws;
    half_t* v_h    = p; p += (size_t)NB * VD;
    half_t* q_h    = p; p += (size_t)NB * QD;
    half_t* cap_h  = p; p += (size_t)NB * NT * CD;
    half_t* wih1_h = p; p += 3 * CD * CD;
    half_t* whh1_h = p; p += 3 * CD * CD;
    half_t* w2cat  = p; p += (size_t)4 * HD * (CD + HD);
    half_t* wfc_h  = p; p += HD * HD;
    half_t* wv_h   = p; p += CD * VD;
    half_t* wq_h   = p; p += CD * QD;
    half_t* h1b0   = p; p += (size_t)NB * CD;
    half_t* h1b1   = p; p += (size_t)NB * CD;
    half_t* atth2  = p; p += (size_t)NB * (CD + HD);
    half_t* gates1 = p; p += (size_t)NB * 3 * CD;
    half_t* gates2 = p; p += (size_t)NB * 4 * HD;
    half_t* h2_all = p; p += (size_t)(NT + 1) * NBHD;   // slice t = h2 entering step t
    half_t* gi1_all = p; p += (size_t)MALL * 3 * CD;    // aliased by fc_out after loop
    half_t* fc_out  = gi1_all;                          // [MALL][HD] <= gi1_all size
    float* fvq = (float*)(p);

    half_t* h1b[2] = {h1b0, h1b1};

    hipMemsetAsync(h1b[0], 0, (size_t)NB * CD * sizeof(half_t), stream);
    hipMemsetAsync(h2_all, 0, NBHD * sizeof(half_t), stream);
    hipMemsetAsync(atth2, 0, (size_t)NB * (CD + HD) * sizeof(half_t), stream);

    auto cvt = [&](const float* s, half_t* d, int n) {
        cvt_kernel<<<n / 1024, 256, 0, stream>>>(s, d, n);
    };
    cvt(v, v_h, NB * VD);
    cvt(q, q_h, NB * QD);
    cvt(cap, cap_h, NB * NT * CD);
    cvt(w_ih1, wih1_h, 3 * CD * CD);
    cvt(w_hh1, whh1_h, 3 * CD * CD);
    cvt(Wfc, wfc_h, HD * HD);
    cvt(Wv, wv_h, CD * VD);
    cvt(Wq, wq_h, CD * QD);
    pack_w2v2_kernel<<<(4 * HD * (CD + HD) / 4) / 256, 256, 0, stream>>>(w_ih2, w_hh2, w2cat);

    fvq_kernel<<<dim3(CD / 64, NB / 128), 256, 0, stream>>>(v_h, wv_h, q_h, wq_h, fvq);
    gi1_gemm_kernel<<<dim3(3 * CD / 64, MALL / 128), 256, 0, stream>>>(cap_h, wih1_h, gi1_all);

    for (int t = 0; t < NT; ++t) {
        const int s = t & 1, d = s ^ 1;
        gates1_gemm_kernel<<<dim3(3 * CD / 64, NB / 128), 256, 0, stream>>>(
            h1b[s], whh1_h, gates1);
        gru1_kernel<<<(NB * CD / 8) / 256, 256, 0, stream>>>(
            gates1, gi1_all, cap_h, b_ih1, b_hh1, h1b[s], h1b[d],
            fvq, cap_len, atth2, alphas, t);
        gates2v2_gemm_kernel<<<dim3(4 * HD / 64, NB / 128), 256, 0, stream>>>(
            atth2, w2cat, gates2);
        gru2v2_kernel<<<(NB * HD / 8) / 256, 256, 0, stream>>>(
            gates2, b_ih2, b_hh2,
            h2_all + (size_t)t * NBHD, h2_all + (size_t)(t + 1) * NBHD,
            cap_len, atth2, t);
    }
    fc_gemm_kernel<<<dim3(HD / 64, MALL / 128), 256, 0, stream>>>(
        h2_all + NBHD, wfc_h, cap_len, fc_out);
    reduce_max_kernel<<<(int)(NBHD / 8 / 256), 256, 0, stream>>>(fc_out, out_max);
}